// Round 1
// baseline (751.715 us; speedup 1.0000x reference)
//
#include <hip/hip_runtime.h>
#include <math.h>

namespace {

constexpr int B = 8, S = 2048, D = 256, H = 4, HD = 64;
constexpr int M = B * S;  // 16384

// ---------------------------------------------------------------------------
// QKV projection: x[M,256] @ W[256,256] + b -> [B][H][S][HD] head-split layout
// Tile: 64(M) x 64(N=one head), BK=32, 256 threads, 4x4 micro-tile per thread.
// ---------------------------------------------------------------------------
__global__ __launch_bounds__(256) void qkv_proj_kernel(
    const float* __restrict__ x,
    const float* __restrict__ Wq, const float* __restrict__ bq,
    const float* __restrict__ Wk, const float* __restrict__ bk,
    const float* __restrict__ Wv, const float* __restrict__ bv,
    float* __restrict__ Qo, float* __restrict__ Ko, float* __restrict__ Vo) {
  const int bx = blockIdx.x;     // M tile
  const int h  = blockIdx.y;     // head == 64-col tile
  const int which = blockIdx.z;  // 0=Q 1=K 2=V
  const float* W    = (which == 0) ? Wq : (which == 1) ? Wk : Wv;
  const float* bias = (which == 0) ? bq : (which == 1) ? bk : bv;
  float* out        = (which == 0) ? Qo : (which == 1) ? Ko : Vo;

  __shared__ float As[64][36];
  __shared__ float Bs[32][68];

  const int tid = threadIdx.x;
  const int tm = tid >> 4, tn = tid & 15;

  float acc[4][4] = {};

  const int ar = tid >> 3;        // 0..31
  const int ac = (tid & 7) * 4;   // 0..28
  const int br = tid >> 4;        // 0..15
  const int bc = (tid & 15) * 4;  // 0..60

  for (int kt = 0; kt < D; kt += 32) {
#pragma unroll
    for (int q = 0; q < 2; ++q) {
      int r = ar + q * 32;
      float4 v = *(const float4*)(x + (size_t)(bx * 64 + r) * D + kt + ac);
      *(float4*)&As[r][ac] = v;
    }
#pragma unroll
    for (int q = 0; q < 2; ++q) {
      int r = br + q * 16;
      float4 v = *(const float4*)(W + (size_t)(kt + r) * D + h * 64 + bc);
      *(float4*)&Bs[r][bc] = v;
    }
    __syncthreads();
#pragma unroll
    for (int kk = 0; kk < 32; ++kk) {
      float a0 = As[tm * 4 + 0][kk];
      float a1 = As[tm * 4 + 1][kk];
      float a2 = As[tm * 4 + 2][kk];
      float a3 = As[tm * 4 + 3][kk];
      float4 b4 = *(float4*)&Bs[kk][tn * 4];
      acc[0][0] += a0 * b4.x; acc[0][1] += a0 * b4.y; acc[0][2] += a0 * b4.z; acc[0][3] += a0 * b4.w;
      acc[1][0] += a1 * b4.x; acc[1][1] += a1 * b4.y; acc[1][2] += a1 * b4.z; acc[1][3] += a1 * b4.w;
      acc[2][0] += a2 * b4.x; acc[2][1] += a2 * b4.y; acc[2][2] += a2 * b4.z; acc[2][3] += a2 * b4.w;
      acc[3][0] += a3 * b4.x; acc[3][1] += a3 * b4.y; acc[3][2] += a3 * b4.z; acc[3][3] += a3 * b4.w;
    }
    __syncthreads();
  }

  float4 b4 = *(const float4*)(bias + h * 64 + tn * 4);
#pragma unroll
  for (int i = 0; i < 4; ++i) {
    int m = bx * 64 + tm * 4 + i;
    int bb = m / S, s = m - bb * S;
    float4 r;
    r.x = acc[i][0] + b4.x;
    r.y = acc[i][1] + b4.y;
    r.z = acc[i][2] + b4.z;
    r.w = acc[i][3] + b4.w;
    *(float4*)(out + (((size_t)bb * H + h) * S + s) * HD + tn * 4) = r;
  }
}

// ---------------------------------------------------------------------------
// Flash attention, fp32. One block per (64-row Q tile, head, batch).
// 256 threads: tm=tid>>4 (row group), tn=tid&15 (col group); 4x4 per thread.
// Online softmax across 32 KV tiles of 64 rows each.
// ---------------------------------------------------------------------------
__global__ __launch_bounds__(256) void attn_kernel(
    const float* __restrict__ Q, const float* __restrict__ K,
    const float* __restrict__ V, float* __restrict__ outc /* [B][S][D] */) {
  const int qt = blockIdx.x;  // 0..31
  const int h  = blockIdx.y;
  const int b  = blockIdx.z;
  const int tid = threadIdx.x;
  const int tm = tid >> 4, tn = tid & 15;

  __shared__ float Qs[64][68];
  __shared__ float Ks[64][68];
  __shared__ float Vs[64][68];
  __shared__ float Ps[64][68];

  const float* Qbase = Q + (((size_t)b * H + h) * S + (size_t)qt * 64) * HD;
  const float* Kbase = K + (((size_t)b * H + h) * S) * HD;
  const float* Vbase = V + (((size_t)b * H + h) * S) * HD;

  const int lr = tid >> 4;        // 0..15
  const int lc = (tid & 15) * 4;  // 0..60

  // Load Q tile, pre-scaled by 1/sqrt(HD) = 0.125
#pragma unroll
  for (int q = 0; q < 4; ++q) {
    int r = lr + q * 16;
    float4 v = *(const float4*)(Qbase + (size_t)r * HD + lc);
    v.x *= 0.125f; v.y *= 0.125f; v.z *= 0.125f; v.w *= 0.125f;
    *(float4*)&Qs[r][lc] = v;
  }

  float m_i[4], l_i[4], o[4][4];
#pragma unroll
  for (int i = 0; i < 4; ++i) {
    m_i[i] = -1e30f;
    l_i[i] = 0.f;
#pragma unroll
    for (int j = 0; j < 4; ++j) o[i][j] = 0.f;
  }
  __syncthreads();

  for (int kt = 0; kt < S / 64; ++kt) {
    // Load K/V tiles
#pragma unroll
    for (int q = 0; q < 4; ++q) {
      int r = lr + q * 16;
      *(float4*)&Ks[r][lc] = *(const float4*)(Kbase + ((size_t)kt * 64 + r) * HD + lc);
      *(float4*)&Vs[r][lc] = *(const float4*)(Vbase + ((size_t)kt * 64 + r) * HD + lc);
    }
    __syncthreads();

    // S = Q @ K^T (Q pre-scaled)
    float sacc[4][4] = {};
#pragma unroll 4
    for (int d0 = 0; d0 < HD; d0 += 4) {
      float4 q4[4], k4[4];
#pragma unroll
      for (int i = 0; i < 4; ++i) q4[i] = *(float4*)&Qs[tm * 4 + i][d0];
#pragma unroll
      for (int j = 0; j < 4; ++j) k4[j] = *(float4*)&Ks[tn * 4 + j][d0];
#pragma unroll
      for (int i = 0; i < 4; ++i)
#pragma unroll
        for (int j = 0; j < 4; ++j)
          sacc[i][j] += q4[i].x * k4[j].x + q4[i].y * k4[j].y +
                        q4[i].z * k4[j].z + q4[i].w * k4[j].w;
    }

    // Online softmax. Rows of this thread: tm*4+i; 16 threads (tn) share a row.
#pragma unroll
    for (int i = 0; i < 4; ++i) {
      float rmax = fmaxf(fmaxf(sacc[i][0], sacc[i][1]), fmaxf(sacc[i][2], sacc[i][3]));
      rmax = fmaxf(rmax, __shfl_xor(rmax, 1, 16));
      rmax = fmaxf(rmax, __shfl_xor(rmax, 2, 16));
      rmax = fmaxf(rmax, __shfl_xor(rmax, 4, 16));
      rmax = fmaxf(rmax, __shfl_xor(rmax, 8, 16));
      float mn = fmaxf(m_i[i], rmax);
      float alpha = __expf(m_i[i] - mn);
      float p0 = __expf(sacc[i][0] - mn);
      float p1 = __expf(sacc[i][1] - mn);
      float p2 = __expf(sacc[i][2] - mn);
      float p3 = __expf(sacc[i][3] - mn);
      float rs = p0 + p1 + p2 + p3;
      rs += __shfl_xor(rs, 1, 16);
      rs += __shfl_xor(rs, 2, 16);
      rs += __shfl_xor(rs, 4, 16);
      rs += __shfl_xor(rs, 8, 16);
      l_i[i] = l_i[i] * alpha + rs;
      m_i[i] = mn;
#pragma unroll
      for (int j = 0; j < 4; ++j) o[i][j] *= alpha;
      float4 pv; pv.x = p0; pv.y = p1; pv.z = p2; pv.w = p3;
      *(float4*)&Ps[tm * 4 + i][tn * 4] = pv;
    }
    __syncthreads();

    // O += P @ V  (cols of this thread: tn*4+j over HD)
#pragma unroll 4
    for (int jj = 0; jj < 64; jj += 4) {
      float4 p4[4];
#pragma unroll
      for (int i = 0; i < 4; ++i) p4[i] = *(float4*)&Ps[tm * 4 + i][jj];
      float4 v0 = *(float4*)&Vs[jj + 0][tn * 4];
      float4 v1 = *(float4*)&Vs[jj + 1][tn * 4];
      float4 v2 = *(float4*)&Vs[jj + 2][tn * 4];
      float4 v3 = *(float4*)&Vs[jj + 3][tn * 4];
#pragma unroll
      for (int i = 0; i < 4; ++i) {
        o[i][0] += p4[i].x * v0.x + p4[i].y * v1.x + p4[i].z * v2.x + p4[i].w * v3.x;
        o[i][1] += p4[i].x * v0.y + p4[i].y * v1.y + p4[i].z * v2.y + p4[i].w * v3.y;
        o[i][2] += p4[i].x * v0.z + p4[i].y * v1.z + p4[i].z * v2.z + p4[i].w * v3.z;
        o[i][3] += p4[i].x * v0.w + p4[i].y * v1.w + p4[i].z * v2.w + p4[i].w * v3.w;
      }
    }
    __syncthreads();
  }

  // Normalize and write concat layout [B][S][H*HD]
#pragma unroll
  for (int i = 0; i < 4; ++i) {
    float inv = 1.0f / l_i[i];
    int s = qt * 64 + tm * 4 + i;
    float4 r;
    r.x = o[i][0] * inv; r.y = o[i][1] * inv; r.z = o[i][2] * inv; r.w = o[i][3] * inv;
    *(float4*)(outc + ((size_t)b * S + s) * D + h * 64 + tn * 4) = r;
  }
}

// ---------------------------------------------------------------------------
// Output projection: A[M,256] @ Wo[256,256] + bo -> out[M,256]
// ---------------------------------------------------------------------------
__global__ __launch_bounds__(256) void out_proj_kernel(
    const float* __restrict__ A, const float* __restrict__ W,
    const float* __restrict__ bias, float* __restrict__ out) {
  const int bx = blockIdx.x;
  const int by = blockIdx.y;

  __shared__ float As[64][36];
  __shared__ float Bs[32][68];

  const int tid = threadIdx.x;
  const int tm = tid >> 4, tn = tid & 15;

  float acc[4][4] = {};

  const int ar = tid >> 3;
  const int ac = (tid & 7) * 4;
  const int br = tid >> 4;
  const int bc = (tid & 15) * 4;

  for (int kt = 0; kt < D; kt += 32) {
#pragma unroll
    for (int q = 0; q < 2; ++q) {
      int r = ar + q * 32;
      *(float4*)&As[r][ac] = *(const float4*)(A + (size_t)(bx * 64 + r) * D + kt + ac);
    }
#pragma unroll
    for (int q = 0; q < 2; ++q) {
      int r = br + q * 16;
      *(float4*)&Bs[r][bc] = *(const float4*)(W + (size_t)(kt + r) * D + by * 64 + bc);
    }
    __syncthreads();
#pragma unroll
    for (int kk = 0; kk < 32; ++kk) {
      float a0 = As[tm * 4 + 0][kk];
      float a1 = As[tm * 4 + 1][kk];
      float a2 = As[tm * 4 + 2][kk];
      float a3 = As[tm * 4 + 3][kk];
      float4 b4 = *(float4*)&Bs[kk][tn * 4];
      acc[0][0] += a0 * b4.x; acc[0][1] += a0 * b4.y; acc[0][2] += a0 * b4.z; acc[0][3] += a0 * b4.w;
      acc[1][0] += a1 * b4.x; acc[1][1] += a1 * b4.y; acc[1][2] += a1 * b4.z; acc[1][3] += a1 * b4.w;
      acc[2][0] += a2 * b4.x; acc[2][1] += a2 * b4.y; acc[2][2] += a2 * b4.z; acc[2][3] += a2 * b4.w;
      acc[3][0] += a3 * b4.x; acc[3][1] += a3 * b4.y; acc[3][2] += a3 * b4.z; acc[3][3] += a3 * b4.w;
    }
    __syncthreads();
  }

  float4 b4 = *(const float4*)(bias + by * 64 + tn * 4);
#pragma unroll
  for (int i = 0; i < 4; ++i) {
    int m = bx * 64 + tm * 4 + i;
    float4 r;
    r.x = acc[i][0] + b4.x;
    r.y = acc[i][1] + b4.y;
    r.z = acc[i][2] + b4.z;
    r.w = acc[i][3] + b4.w;
    *(float4*)(out + (size_t)m * D + by * 64 + tn * 4) = r;
  }
}

}  // namespace

extern "C" void kernel_launch(void* const* d_in, const int* in_sizes, int n_in,
                              void* d_out, int out_size, void* d_ws, size_t ws_size,
                              hipStream_t stream) {
  const float* x  = (const float*)d_in[0];
  const float* Wq = (const float*)d_in[1];
  const float* bq = (const float*)d_in[2];
  const float* Wk = (const float*)d_in[3];
  const float* bk = (const float*)d_in[4];
  const float* Wv = (const float*)d_in[5];
  const float* bv = (const float*)d_in[6];
  const float* Wo = (const float*)d_in[7];
  const float* bo = (const float*)d_in[8];
  float* out = (float*)d_out;

  const size_t per = (size_t)B * H * S * HD;  // 4,194,304 floats
  float* Q = (float*)d_ws;
  float* K = Q + per;
  float* V = K + per;
  float* A = V + per;

  qkv_proj_kernel<<<dim3(M / 64, H, 3), 256, 0, stream>>>(
      x, Wq, bq, Wk, bk, Wv, bv, Q, K, V);
  attn_kernel<<<dim3(S / 64, H, B), 256, 0, stream>>>(Q, K, V, A);
  out_proj_kernel<<<dim3(M / 64, D / 64), 256, 0, stream>>>(A, Wo, bo, out);
}

// Round 2
// 243.230 us; speedup vs baseline: 3.0906x; 3.0906x over previous
//
#include <hip/hip_runtime.h>
#include <hip/hip_bf16.h>
#include <math.h>

namespace {

constexpr int B = 8, S = 2048, D = 256, H = 4, HD = 64;
constexpr int M = B * S;  // 16384

typedef __attribute__((ext_vector_type(8))) short bf16x8;
typedef __attribute__((ext_vector_type(4))) short short4v;
typedef __attribute__((ext_vector_type(4))) float f32x4;

__device__ inline short f2bf(float x) {
  __hip_bfloat16 h = __float2bfloat16(x);
  short s;
  __builtin_memcpy(&s, &h, 2);
  return s;
}

__device__ inline f32x4 mfma16(bf16x8 a, bf16x8 b, f32x4 c) {
  return __builtin_amdgcn_mfma_f32_16x16x32_bf16(a, b, c, 0, 0, 0);
}

// ---------------------------------------------------------------------------
// QKV projection (fp32 math): x[M,256] @ W[256,256] + b.
// Outputs bf16: Q (pre-scaled by 1/8) and K in [B][H][S][HD];
// V transposed to [B][H][HD][S] so attention's PV B-fragments are contiguous.
// ---------------------------------------------------------------------------
__global__ __launch_bounds__(256) void qkv_proj_kernel(
    const float* __restrict__ x,
    const float* __restrict__ Wq, const float* __restrict__ bq,
    const float* __restrict__ Wk, const float* __restrict__ bk,
    const float* __restrict__ Wv, const float* __restrict__ bv,
    short* __restrict__ Qo, short* __restrict__ Ko, short* __restrict__ Vo) {
  const int bx = blockIdx.x;     // M tile
  const int h  = blockIdx.y;     // head == 64-col tile
  const int which = blockIdx.z;  // 0=Q 1=K 2=V
  const float* W    = (which == 0) ? Wq : (which == 1) ? Wk : Wv;
  const float* bias = (which == 0) ? bq : (which == 1) ? bk : bv;

  __shared__ float As[64][36];
  __shared__ float Bs[32][68];

  const int tid = threadIdx.x;
  const int tm = tid >> 4, tn = tid & 15;

  float acc[4][4] = {};

  const int ar = tid >> 3;        // 0..31
  const int ac = (tid & 7) * 4;   // 0..28
  const int br = tid >> 4;        // 0..15
  const int bc = (tid & 15) * 4;  // 0..60

  for (int kt = 0; kt < D; kt += 32) {
#pragma unroll
    for (int q = 0; q < 2; ++q) {
      int r = ar + q * 32;
      *(float4*)&As[r][ac] = *(const float4*)(x + (size_t)(bx * 64 + r) * D + kt + ac);
    }
#pragma unroll
    for (int q = 0; q < 2; ++q) {
      int r = br + q * 16;
      *(float4*)&Bs[r][bc] = *(const float4*)(W + (size_t)(kt + r) * D + h * 64 + bc);
    }
    __syncthreads();
#pragma unroll
    for (int kk = 0; kk < 32; ++kk) {
      float a0 = As[tm * 4 + 0][kk];
      float a1 = As[tm * 4 + 1][kk];
      float a2 = As[tm * 4 + 2][kk];
      float a3 = As[tm * 4 + 3][kk];
      float4 b4 = *(float4*)&Bs[kk][tn * 4];
      acc[0][0] += a0 * b4.x; acc[0][1] += a0 * b4.y; acc[0][2] += a0 * b4.z; acc[0][3] += a0 * b4.w;
      acc[1][0] += a1 * b4.x; acc[1][1] += a1 * b4.y; acc[1][2] += a1 * b4.z; acc[1][3] += a1 * b4.w;
      acc[2][0] += a2 * b4.x; acc[2][1] += a2 * b4.y; acc[2][2] += a2 * b4.z; acc[2][3] += a2 * b4.w;
      acc[3][0] += a3 * b4.x; acc[3][1] += a3 * b4.y; acc[3][2] += a3 * b4.z; acc[3][3] += a3 * b4.w;
    }
    __syncthreads();
  }

  const int m0 = bx * 64 + tm * 4;
  const int bb = m0 / S, s0 = m0 - bb * S;
  const size_t bh = (size_t)bb * H + h;
  float bias4[4];
#pragma unroll
  for (int j = 0; j < 4; ++j) bias4[j] = bias[h * 64 + tn * 4 + j];

  if (which == 2) {
    // V: transposed write [B][H][HD][S]
#pragma unroll
    for (int j = 0; j < 4; ++j) {
      short4v r;
#pragma unroll
      for (int i = 0; i < 4; ++i) r[i] = f2bf(acc[i][j] + bias4[j]);
      *(short4v*)(Vo + (bh * HD + tn * 4 + j) * S + s0) = r;
    }
  } else {
    const float scale = (which == 0) ? 0.125f : 1.0f;  // fold 1/sqrt(HD) into Q
    short* out = (which == 0) ? Qo : Ko;
#pragma unroll
    for (int i = 0; i < 4; ++i) {
      short4v r;
#pragma unroll
      for (int j = 0; j < 4; ++j) r[j] = f2bf((acc[i][j] + bias4[j]) * scale);
      *(short4v*)(out + (bh * S + s0 + i) * HD + tn * 4) = r;
    }
  }
}

// ---------------------------------------------------------------------------
// Flash attention with bf16 MFMA (16x16x32), fp32 softmax/accum.
// Block = 256 threads = 4 waves; block owns 64 q-rows of one (b,h);
// wave w owns q-rows [w*16, w*16+16). KV tiles of 64, online softmax.
// Q in registers; K/V reg-staged into padded LDS; P through per-wave LDS.
// ---------------------------------------------------------------------------
__global__ __launch_bounds__(256) void attn_mfma_kernel(
    const short* __restrict__ Q, const short* __restrict__ K,
    const short* __restrict__ Vt, float* __restrict__ outc /* [B][S][D] */) {
  const int qt = blockIdx.x;  // 0..31
  const int h  = blockIdx.y;
  const int b  = blockIdx.z;
  const int tid = threadIdx.x;
  const int wid = tid >> 6;
  const int lane = tid & 63;
  const int l15 = lane & 15;   // fragment row/col within 16
  const int l4  = lane >> 4;   // k-block selector

  __shared__ short Ks[64][72];  // [kv][d], padded
  __shared__ short Vs[64][72];  // [d][kv], padded
  __shared__ short Ps[64][72];  // [q][kv], per-wave 16-row slices

  const size_t bh = (size_t)b * H + h;

  // Q A-fragments: fixed for whole kernel. lane -> row l15, k-cols l4*8..+7
  const short* Qg = Q + (bh * S + (size_t)qt * 64 + wid * 16 + l15) * HD + l4 * 8;
  const bf16x8 aQ0 = *(const bf16x8*)Qg;         // d 0..31
  const bf16x8 aQ1 = *(const bf16x8*)(Qg + 32);  // d 32..63

  // staging: thread t covers row srow, 16 cols at scol (two 16B pieces)
  const int srow = tid >> 2;
  const int scol = (tid & 3) * 16;
  const short* Kg = K + bh * S * HD;   // [s][d]
  const short* Vg = Vt + bh * HD * S;  // [d][s]

  bf16x8 kr0, kr1, vr0, vr1;
  {
    const int kt = 0;
    kr0 = *(const bf16x8*)(Kg + (size_t)(kt * 64 + srow) * HD + scol);
    kr1 = *(const bf16x8*)(Kg + (size_t)(kt * 64 + srow) * HD + scol + 8);
    vr0 = *(const bf16x8*)(Vg + (size_t)srow * S + kt * 64 + scol);
    vr1 = *(const bf16x8*)(Vg + (size_t)srow * S + kt * 64 + scol + 8);
  }

  f32x4 o[4];  // d-tiles of 16; rows match score fragment rows
  float m_i[4], l_i[4];
#pragma unroll
  for (int r = 0; r < 4; ++r) {
    o[r] = f32x4{0.f, 0.f, 0.f, 0.f};
    m_i[r] = -1e30f;
    l_i[r] = 0.f;
  }

  for (int kt = 0; kt < S / 64; ++kt) {
    __syncthreads();  // previous tile's LDS consumers done
    *(bf16x8*)&Ks[srow][scol]     = kr0;
    *(bf16x8*)&Ks[srow][scol + 8] = kr1;
    *(bf16x8*)&Vs[srow][scol]     = vr0;
    *(bf16x8*)&Vs[srow][scol + 8] = vr1;
    if (kt + 1 < S / 64) {  // prefetch next tile into regs (overlaps compute)
      const int kn = kt + 1;
      kr0 = *(const bf16x8*)(Kg + (size_t)(kn * 64 + srow) * HD + scol);
      kr1 = *(const bf16x8*)(Kg + (size_t)(kn * 64 + srow) * HD + scol + 8);
      vr0 = *(const bf16x8*)(Vg + (size_t)srow * S + kn * 64 + scol);
      vr1 = *(const bf16x8*)(Vg + (size_t)srow * S + kn * 64 + scol + 8);
    }
    __syncthreads();  // K/V tile visible

    // --- S = Q @ K^T (Q pre-scaled by 1/8) ---
    f32x4 sc[4];
#pragma unroll
    for (int nt = 0; nt < 4; ++nt) sc[nt] = f32x4{0.f, 0.f, 0.f, 0.f};
#pragma unroll
    for (int nt = 0; nt < 4; ++nt) {
      bf16x8 b0 = *(const bf16x8*)&Ks[nt * 16 + l15][l4 * 8];
      bf16x8 b1 = *(const bf16x8*)&Ks[nt * 16 + l15][32 + l4 * 8];
      sc[nt] = mfma16(aQ0, b0, sc[nt]);
      sc[nt] = mfma16(aQ1, b1, sc[nt]);
    }

    // --- online softmax (rows = (l4*4+r) within wave's 16) ---
#pragma unroll
    for (int r = 0; r < 4; ++r) {
      float smax = fmaxf(fmaxf(sc[0][r], sc[1][r]), fmaxf(sc[2][r], sc[3][r]));
      smax = fmaxf(smax, __shfl_xor(smax, 1));
      smax = fmaxf(smax, __shfl_xor(smax, 2));
      smax = fmaxf(smax, __shfl_xor(smax, 4));
      smax = fmaxf(smax, __shfl_xor(smax, 8));
      float mn = fmaxf(m_i[r], smax);
      float alpha = __expf(m_i[r] - mn);
      m_i[r] = mn;
      float rs = 0.f;
#pragma unroll
      for (int nt = 0; nt < 4; ++nt) {
        float p = __expf(sc[nt][r] - mn);
        rs += p;
        Ps[wid * 16 + l4 * 4 + r][nt * 16 + l15] = f2bf(p);
      }
      rs += __shfl_xor(rs, 1);
      rs += __shfl_xor(rs, 2);
      rs += __shfl_xor(rs, 4);
      rs += __shfl_xor(rs, 8);
      l_i[r] = l_i[r] * alpha + rs;
#pragma unroll
      for (int dt = 0; dt < 4; ++dt) o[dt][r] *= alpha;
    }

    // --- O += P @ V --- (A from per-wave Ps rows; B from Vs[d][kv])
    bf16x8 pa0 = *(const bf16x8*)&Ps[wid * 16 + l15][l4 * 8];
    bf16x8 pa1 = *(const bf16x8*)&Ps[wid * 16 + l15][32 + l4 * 8];
#pragma unroll
    for (int dt = 0; dt < 4; ++dt) {
      bf16x8 b0 = *(const bf16x8*)&Vs[dt * 16 + l15][l4 * 8];
      bf16x8 b1 = *(const bf16x8*)&Vs[dt * 16 + l15][32 + l4 * 8];
      o[dt] = mfma16(pa0, b0, o[dt]);
      o[dt] = mfma16(pa1, b1, o[dt]);
    }
  }

  // normalize + write concat [B][S][H*HD] fp32
#pragma unroll
  for (int r = 0; r < 4; ++r) {
    float inv = 1.0f / l_i[r];
    int sq = qt * 64 + wid * 16 + l4 * 4 + r;
    float* op = outc + ((size_t)b * S + sq) * D + h * 64 + l15;
    op[0]  = o[0][r] * inv;
    op[16] = o[1][r] * inv;
    op[32] = o[2][r] * inv;
    op[48] = o[3][r] * inv;
  }
}

// ---------------------------------------------------------------------------
// Output projection: A[M,256] @ Wo[256,256] + bo -> out[M,256] (fp32)
// ---------------------------------------------------------------------------
__global__ __launch_bounds__(256) void out_proj_kernel(
    const float* __restrict__ A, const float* __restrict__ W,
    const float* __restrict__ bias, float* __restrict__ out) {
  const int bx = blockIdx.x;
  const int by = blockIdx.y;

  __shared__ float As[64][36];
  __shared__ float Bs[32][68];

  const int tid = threadIdx.x;
  const int tm = tid >> 4, tn = tid & 15;

  float acc[4][4] = {};

  const int ar = tid >> 3;
  const int ac = (tid & 7) * 4;
  const int br = tid >> 4;
  const int bc = (tid & 15) * 4;

  for (int kt = 0; kt < D; kt += 32) {
#pragma unroll
    for (int q = 0; q < 2; ++q) {
      int r = ar + q * 32;
      *(float4*)&As[r][ac] = *(const float4*)(A + (size_t)(bx * 64 + r) * D + kt + ac);
    }
#pragma unroll
    for (int q = 0; q < 2; ++q) {
      int r = br + q * 16;
      *(float4*)&Bs[r][bc] = *(const float4*)(W + (size_t)(kt + r) * D + by * 64 + bc);
    }
    __syncthreads();
#pragma unroll
    for (int kk = 0; kk < 32; ++kk) {
      float a0 = As[tm * 4 + 0][kk];
      float a1 = As[tm * 4 + 1][kk];
      float a2 = As[tm * 4 + 2][kk];
      float a3 = As[tm * 4 + 3][kk];
      float4 b4 = *(float4*)&Bs[kk][tn * 4];
      acc[0][0] += a0 * b4.x; acc[0][1] += a0 * b4.y; acc[0][2] += a0 * b4.z; acc[0][3] += a0 * b4.w;
      acc[1][0] += a1 * b4.x; acc[1][1] += a1 * b4.y; acc[1][2] += a1 * b4.z; acc[1][3] += a1 * b4.w;
      acc[2][0] += a2 * b4.x; acc[2][1] += a2 * b4.y; acc[2][2] += a2 * b4.z; acc[2][3] += a2 * b4.w;
      acc[3][0] += a3 * b4.x; acc[3][1] += a3 * b4.y; acc[3][2] += a3 * b4.z; acc[3][3] += a3 * b4.w;
    }
    __syncthreads();
  }

  float4 b4 = *(const float4*)(bias + by * 64 + tn * 4);
#pragma unroll
  for (int i = 0; i < 4; ++i) {
    int m = bx * 64 + tm * 4 + i;
    float4 r;
    r.x = acc[i][0] + b4.x;
    r.y = acc[i][1] + b4.y;
    r.z = acc[i][2] + b4.z;
    r.w = acc[i][3] + b4.w;
    *(float4*)(out + (size_t)m * D + by * 64 + tn * 4) = r;
  }
}

}  // namespace

extern "C" void kernel_launch(void* const* d_in, const int* in_sizes, int n_in,
                              void* d_out, int out_size, void* d_ws, size_t ws_size,
                              hipStream_t stream) {
  const float* x  = (const float*)d_in[0];
  const float* Wq = (const float*)d_in[1];
  const float* bq = (const float*)d_in[2];
  const float* Wk = (const float*)d_in[3];
  const float* bk = (const float*)d_in[4];
  const float* Wv = (const float*)d_in[5];
  const float* bv = (const float*)d_in[6];
  const float* Wo = (const float*)d_in[7];
  const float* bo = (const float*)d_in[8];
  float* out = (float*)d_out;

  const size_t per = (size_t)B * H * S * HD;  // 4,194,304 elems
  short* Qbf = (short*)d_ws;        // bf16, pre-scaled
  short* Kbf = Qbf + per;           // bf16
  short* Vtb = Kbf + per;           // bf16, transposed [B][H][HD][S]
  float* A   = (float*)(Vtb + per); // fp32 attn concat [B][S][D]

  qkv_proj_kernel<<<dim3(M / 64, H, 3), 256, 0, stream>>>(
      x, Wq, bq, Wk, bk, Wv, bv, Qbf, Kbf, Vtb);
  attn_mfma_kernel<<<dim3(S / 64, H, B), 256, 0, stream>>>(Qbf, Kbf, Vtb, A);
  out_proj_kernel<<<dim3(M / 64, D / 64), 256, 0, stream>>>(A, Wo, bo, out);
}